// Round 13
// baseline (476.662 us; speedup 1.0000x reference)
//
#include <hip/hip_runtime.h>
#include <cstdint>
#include <cstddef>

// Problem constants (from reference). Inputs/outputs are fp32 (verified round 4).
#define BN_ 2
#define TQ_ 1024
#define TK_ 2048
#define DQ_ 1024
#define DC_ 768
#define NH_ 16
#define DH_ 64
#define TOPK_ 64

typedef unsigned short u16;
typedef __attribute__((ext_vector_type(8))) short short8;   // 8 bf16 MFMA frag
typedef __attribute__((ext_vector_type(8))) u16   ushort8;  // 16B vector load
typedef __attribute__((ext_vector_type(4))) float floatx4;  // MFMA acc / float4

__device__ __forceinline__ float bf2f(u16 u) { return __uint_as_float(((unsigned)u) << 16); }
__device__ __forceinline__ u16 f2bf(float f) {  // round-to-nearest-even
    unsigned u = __float_as_uint(f);
    u += 0x7FFFu + ((u >> 16) & 1u);
    return (u16)(u >> 16);
}
__device__ __forceinline__ float definite(float v, float repl) {
    return ((__float_as_uint(v) & 0x7F800000u) == 0x7F800000u) ? repl : v;
}
// monotone float<->uint mapping (ascending)
__device__ __forceinline__ unsigned mono(float f) {
    unsigned u = __float_as_uint(f);
    return (u & 0x80000000u) ? ~u : (u | 0x80000000u);
}
__device__ __forceinline__ float invmono(unsigned u) {
    return __uint_as_float((u & 0x80000000u) ? (u & 0x7FFFFFFFu) : ~u);
}
// 16-lane-group reductions (xor offsets 1,2,4,8 stay inside row-of-16 -> DPP)
__device__ __forceinline__ int gsum16(int x) {
#pragma unroll
    for (int o = 1; o < 16; o <<= 1) x += __shfl_xor(x, o);
    return x;
}
__device__ __forceinline__ int gmin16(int x) {
#pragma unroll
    for (int o = 1; o < 16; o <<= 1) { int y = __shfl_xor(x, o); x = (y < x) ? y : x; }
    return x;
}
__device__ __forceinline__ unsigned gmin16u(unsigned x) {
#pragma unroll
    for (int o = 1; o < 16; o <<= 1) { unsigned y = __shfl_xor((int)x, o); x = (y < x) ? y : x; }
    return x;
}
__device__ __forceinline__ unsigned gmax16u(unsigned x) {
#pragma unroll
    for (int o = 1; o < 16; o <<= 1) { unsigned y = __shfl_xor((int)x, o); x = (y > x) ? y : x; }
    return x;
}
__device__ __forceinline__ float gmax16f(float x) {
#pragma unroll
    for (int o = 1; o < 16; o <<= 1) x = fmaxf(x, __shfl_xor(x, o));
    return x;
}
__device__ __forceinline__ float gsum16f(float x) {
#pragma unroll
    for (int o = 1; o < 16; o <<= 1) x += __shfl_xor(x, o);
    return x;
}

// diagnostic: fill output with a recognizable constant (fp32 out)
__global__ void marker_kernel(float* __restrict__ out, int n, float val) {
    const int i = blockIdx.x * 256 + threadIdx.x;
    if (i < n) out[i] = val;
}

// ---------------------------------------------------------------------------
// Exact top-64 selection over NV values/lane spread across a 16-lane group.
// um[] mono-mapped (z-biased), kk[] keys; base added back before invmono.
// hb = highest bit to search; early-exit when count==64 (set remains exact:
// {u >= X} has exactly 64). Compact >X then tie-fill ==X ascending-key.
// Returns xval = invmono(base+X). NOTE: with early exit X can be BELOW the
// true min of the kept set — callers using the return as a filter threshold
// must clamp (see compact-select path).
template <int NV>
__device__ __forceinline__ float select_topk(const unsigned (&um)[NV], const int (&kk)[NV],
                                             unsigned base, int hb, int l16,
                                             float* cvrow, int* ckrow) {
    unsigned X = 0u;
    bool done = false;
    for (int bit = hb; bit >= 0; --bit) {
        const unsigned C = X | (1u << bit);
        int c = 0;
#pragma unroll
        for (int j = 0; j < NV; ++j) c += (um[j] >= C) ? 1 : 0;
        c = gsum16(c);
        if (!done && c >= 64) X = C;
        if (c == 64) done = true;
        if (__all(done)) break;
    }
    // compact strictly-greater
    int myGt = 0;
#pragma unroll
    for (int j = 0; j < NV; ++j) myGt += (um[j] > X) ? 1 : 0;
    const int totalGt = gsum16(myGt);
    int pre = myGt;
#pragma unroll
    for (int off = 1; off < 16; off <<= 1) {
        const int tv = __shfl_up(pre, off);
        if (l16 >= off) pre += tv;
    }
    int wpos = pre - myGt;
#pragma unroll
    for (int j = 0; j < NV; ++j) {
        if (um[j] > X) {
            cvrow[wpos] = invmono(base + um[j]);
            ckrow[wpos] = kk[j];
            ++wpos;
        }
    }
    // tie-fill remaining slots with ==X entries, ascending key
    const float xval = invmono(base + X);
    int remaining = 64 - totalGt;
    int pos = totalGt;
    int lastkey = -1;
    while (remaining > 0) {
        int mykey = 0x7FFFFFFF;
#pragma unroll
        for (int j = 0; j < NV; ++j)
            if (um[j] == X && kk[j] > lastkey && kk[j] < mykey) mykey = kk[j];
        const int mn = gmin16(mykey);
        if (mn == 0x7FFFFFFF) break;
        if (mykey == mn) { cvrow[pos] = xval; ckrow[pos] = mn; }
        lastkey = mn;
        ++pos; --remaining;
    }
    return xval;
}

// ---------------------------------------------------------------------------
// Transpose + hi/lo-split: W fp32 [K][N] -> Wh,Wl bf16 [N][K]
__global__ void __launch_bounds__(256) tsplit(const float* __restrict__ W,
                                              u16* __restrict__ Wh, u16* __restrict__ Wl,
                                              int K, int N) {
    __shared__ float t[32][33];
    const int x = threadIdx.x & 31, y = threadIdx.x >> 5;   // y in 0..7
    const int bn = blockIdx.x * 32, bk = blockIdx.y * 32;
#pragma unroll
    for (int i = 0; i < 32; i += 8) t[y + i][x] = W[(size_t)(bk + y + i) * N + bn + x];
    __syncthreads();
#pragma unroll
    for (int i = 0; i < 32; i += 8) {
        const float f = t[x][y + i];            // = W[bk+x][bn+y+i]
        const u16 hi = f2bf(f);
        const size_t o = (size_t)(bn + y + i) * K + bk + x;
        Wh[o] = hi;
        Wl[o] = f2bf(f - bf2f(hi));
    }
}

// ---------------------------------------------------------------------------
// GEMM (round-11 proven): C[M][N] = A[M][K] * W[K][N] + bias, * scale.
// B pre-transposed & split: Bh/Bl bf16 [N][K]. Tile 64(M) x 128(N), BK=64.
// XOR-swizzled UNPADDED LDS: row m chunk c stored at slot m*8 + (c ^ (m&7)).
// 4 waves 2x2: wave tile 32(m) x 64(n) = 2x4 mfma_16x16x32, 3-term split
// (ah*bh + al*bh + ah*bl). LDS 48KB -> 3 WG/CU.
// ASPLIT 0: A fp32 (split at stage). ASPLIT 1: A bf16 hi/lo pair.
// OMODE 0: fp32 out. 1: bf16 out. 2: bf16 hi/lo pair out.
template <int ASPLIT, int OMODE>
__global__ void __launch_bounds__(256) gemm3(
    const void* __restrict__ Ap, const void* __restrict__ Alp,
    const u16* __restrict__ Bh, const u16* __restrict__ Bl,
    const float* __restrict__ bias, float scale,
    void* __restrict__ out0, void* __restrict__ out1,
    int M, int N, int K) {
    __shared__ u16 Ahs[64 * 64];    // 8 KB   [m][k] hi, swizzled
    __shared__ u16 Als[64 * 64];    // 8 KB   lo
    __shared__ u16 Bhs[128 * 64];   // 16 KB  [n][k] hi, swizzled
    __shared__ u16 Bls[128 * 64];   // 16 KB  lo

    const int tid = threadIdx.x;
    const int lane = tid & 63, wave = tid >> 6;
    const int wm = wave >> 1, wn = wave & 1;
    const int quad = lane >> 4, l16 = lane & 15;
    const int bm = blockIdx.y * 64, bn = blockIdx.x * 128;

    floatx4 acc[2][4] = {};

    for (int k0 = 0; k0 < K; k0 += 64) {
        __syncthreads();
        // ---- stage A: 64 rows x 64 cols = 512 slots of 8 elems, 2 per thread
#pragma unroll
        for (int s2 = 0; s2 < 2; ++s2) {
            const int slot = tid + s2 * 256;
            const int m = slot >> 3, cpos = slot & 7;
            const int c = cpos ^ (m & 7);
            const size_t aoff = (size_t)(bm + m) * K + k0 + c * 8;
            if constexpr (ASPLIT == 0) {
                const float* f = (const float*)Ap + aoff;
                const floatx4 a = *(const floatx4*)f;
                const floatx4 b = *(const floatx4*)(f + 4);
                ushort8 hi, lo;
#pragma unroll
                for (int j = 0; j < 4; ++j) {
                    u16 t = f2bf(a[j]);
                    hi[j] = t; lo[j] = f2bf(a[j] - bf2f(t));
                    t = f2bf(b[j]);
                    hi[4 + j] = t; lo[4 + j] = f2bf(b[j] - bf2f(t));
                }
                *(ushort8*)&Ahs[slot * 8] = hi;
                *(ushort8*)&Als[slot * 8] = lo;
            } else {
                *(ushort8*)&Ahs[slot * 8] = *(const ushort8*)((const u16*)Ap  + aoff);
                *(ushort8*)&Als[slot * 8] = *(const ushort8*)((const u16*)Alp + aoff);
            }
        }
        // ---- stage B: 128 rows x 64 cols = 1024 slots, 4 per thread
#pragma unroll
        for (int s4 = 0; s4 < 4; ++s4) {
            const int slot = tid + s4 * 256;
            const int n = slot >> 3, cpos = slot & 7;
            const int c = cpos ^ (n & 7);
            const size_t boff = (size_t)(bn + n) * K + k0 + c * 8;
            *(ushort8*)&Bhs[slot * 8] = *(const ushort8*)(Bh + boff);
            *(ushort8*)&Bls[slot * 8] = *(const ushort8*)(Bl + boff);
        }
        __syncthreads();
#pragma unroll
        for (int s = 0; s < 2; ++s) {
            short8 ah[2], al[2], bh[4], bl[4];
#pragma unroll
            for (int mt = 0; mt < 2; ++mt) {
                const int m = wm * 32 + mt * 16 + l16;
                const int cs = s * 4 + quad;
                const int slot = m * 8 + (cs ^ (m & 7));
                ah[mt] = *(const short8*)&Ahs[slot * 8];
                al[mt] = *(const short8*)&Als[slot * 8];
            }
#pragma unroll
            for (int nt = 0; nt < 4; ++nt) {
                const int n = wn * 64 + nt * 16 + l16;
                const int cs = s * 4 + quad;
                const int slot = n * 8 + (cs ^ (n & 7));
                bh[nt] = *(const short8*)&Bhs[slot * 8];
                bl[nt] = *(const short8*)&Bls[slot * 8];
            }
#pragma unroll
            for (int mt = 0; mt < 2; ++mt)
#pragma unroll
                for (int nt = 0; nt < 4; ++nt) {
                    acc[mt][nt] = __builtin_amdgcn_mfma_f32_16x16x32_bf16(ah[mt], bh[nt], acc[mt][nt], 0, 0, 0);
                    acc[mt][nt] = __builtin_amdgcn_mfma_f32_16x16x32_bf16(al[mt], bh[nt], acc[mt][nt], 0, 0, 0);
                    acc[mt][nt] = __builtin_amdgcn_mfma_f32_16x16x32_bf16(ah[mt], bl[nt], acc[mt][nt], 0, 0, 0);
                }
        }
    }

#pragma unroll
    for (int mt = 0; mt < 2; ++mt) {
#pragma unroll
        for (int nt = 0; nt < 4; ++nt) {
            const int col = bn + wn * 64 + nt * 16 + l16;
            const float bcol = bias[col];
#pragma unroll
            for (int r = 0; r < 4; ++r) {
                const int row = bm + wm * 32 + mt * 16 + quad * 4 + r;
                const float val = definite((acc[mt][nt][r] + bcol) * scale, 0.0f);
                const size_t idx = (size_t)row * N + col;
                if constexpr (OMODE == 0) {
                    ((float*)out0)[idx] = val;
                } else if constexpr (OMODE == 1) {
                    ((u16*)out0)[idx] = f2bf(val);
                } else {
                    const u16 hi = f2bf(val);
                    ((u16*)out0)[idx] = hi;
                    ((u16*)out1)[idx] = f2bf(val - bf2f(hi));
                }
            }
        }
    }
}

// ---------------------------------------------------------------------------
// Fused attention: per WG = one (b, h, 16-query tile).
// Split-bf16 MFMA logits (fp32-accurate). 8 OCTETS of 256 keys (was 4
// quarters of 512) — lg shrinks 32KB->16KB, total LDS 24576 B -> 6 WG/CU.
// Octet 0: full logits in lg[16][256] + 20-value early-exit select.
// Octets 1-7: candidate compaction — logits strictly above the stored filter
// threshold th (float slot 254; X from select, a LOWER BOUND on carry-min)
// pushed via LDS atomic counter (int slot 255) into values [0..119] / keys
// int-slots [120..239] (cap 120; E[n]=32..8, overflow ~impossible & capped
// soundly). Compact select: 12 values/lane (8 cand + 4 carry) in z-space vs
// the TRUE carry-min cm; mono(v) <= cm candidates clamped to inert pads
// (z=0, key=INT_MAX) — the round-11 underflow fix. Selection invariant
// (exact running top-64, ascending-key ties) is partition-independent ->
// same selected set as the quarter scheme. Output hi/lo in-place Qhi/Qlo.
__global__ void __launch_bounds__(256, 6) attn_topk(
    const u16* Qhi, const u16* Qlo,     // aliased with outputs - no __restrict__
    const u16* __restrict__ Khi, const u16* __restrict__ Klo,
    const u16* __restrict__ Vb16, const void* __restrict__ maskp,
    u16* attnH, u16* attnL) {
    __shared__ float lg[16][256];     // 16384 B
    __shared__ float cval[16][64];    // 4096 B
    __shared__ int   ckey[16][64];    // 4096 B  -> total 24576 B
    #define LGI(row) ((int*)&lg[row][0])

    const int tid = threadIdx.x;
    const int lane = tid & 63, wave = tid >> 6;
    const int quad = lane >> 4, l16 = lane & 15;
    const int rowg = wave * 4 + quad;              // this lane's selection row
    const int b = blockIdx.z, h = blockIdx.y, q0 = blockIdx.x * 16;

    // ---- mask dtype probe: per-wave, barrier-free (first 1024 u16 = 2 KB)
    int mmode;
    {
        bool cbyte = false, cbf = false, cf32 = false;
#pragma unroll
        for (int j = 0; j < 16; ++j) {
            const int i = lane + 64 * j;
            const unsigned v = ((const u16*)maskp)[i];
            cbyte |= (v == 0x0100u || v == 0x0101u) || ((i & 1) && v == 0x0001u);
            cbf   |= (!(i & 1)) && v == 0x3F80u;
            cf32  |= (i & 1) && v == 0x3F80u;
        }
        const bool abf = __any(cbf), af32 = __any(cf32), abyte = __any(cbyte);
        mmode = abf ? 2 : (af32 ? 3 : (abyte ? 1 : 0));
    }

    // ---- Q fragments (A-operand: m=lane&15, k=quad*8+j), two k-steps of 32
    short8 qh[2], ql[2];
    {
        const size_t base = (size_t)(b * TQ_ + q0 + l16) * DQ_ + h * DH_ + quad * 8;
        qh[0] = *(const short8*)(Qhi + base);
        qh[1] = *(const short8*)(Qhi + base + 32);
        ql[0] = *(const short8*)(Qlo + base);
        ql[1] = *(const short8*)(Qlo + base + 32);
    }

    // init carry to -inf with distinct keys (first barrier below covers this)
    for (int i = tid; i < 16 * 64; i += 256) {
        cval[i >> 6][i & 63] = __uint_as_float(0xFF800000u);
        ckey[i >> 6][i & 63] = i & 63;
    }

    for (int oct = 0; oct < 8; ++oct) {
        if (oct == 0) {
            // ---- full logit phase: 256 keys, each wave 64 keys x 16 rows
#pragma unroll
            for (int t = 0; t < 4; ++t) {
                const int key = wave * 64 + t * 16 + l16;
                const size_t kb = (size_t)(b * TK_ + key) * DQ_ + h * DH_ + quad * 8;
                const short8 kh0 = *(const short8*)(Khi + kb);
                const short8 kh1 = *(const short8*)(Khi + kb + 32);
                const short8 kl0 = *(const short8*)(Klo + kb);
                const short8 kl1 = *(const short8*)(Klo + kb + 32);
                floatx4 acc = {};
                acc = __builtin_amdgcn_mfma_f32_16x16x32_bf16(qh[0], kh0, acc, 0, 0, 0);
                acc = __builtin_amdgcn_mfma_f32_16x16x32_bf16(ql[0], kh0, acc, 0, 0, 0);
                acc = __builtin_amdgcn_mfma_f32_16x16x32_bf16(qh[0], kl0, acc, 0, 0, 0);
                acc = __builtin_amdgcn_mfma_f32_16x16x32_bf16(qh[1], kh1, acc, 0, 0, 0);
                acc = __builtin_amdgcn_mfma_f32_16x16x32_bf16(ql[1], kh1, acc, 0, 0, 0);
                acc = __builtin_amdgcn_mfma_f32_16x16x32_bf16(qh[1], kl1, acc, 0, 0, 0);
                const int midx = b * TK_ + key;
                bool masked;
                if (mmode == 2)      masked = ((const u16*)maskp)[midx] != 0;
                else if (mmode == 3) masked = ((const float*)maskp)[midx] != 0.0f;
                else if (mmode == 1) masked = ((const unsigned char*)maskp)[midx] != 0;
                else                 masked = ((const int*)maskp)[midx] != 0;
#pragma unroll
                for (int r = 0; r < 4; ++r)
                    lg[quad * 4 + r][key] = masked ? -3.0e38f : definite(acc[r], -3.0e38f);
            }
            __syncthreads();

            // ---- full select over 16 new + 4 carry
            unsigned um[20]; int kk[20];
#pragma unroll
            for (int j = 0; j < 16; ++j) {
                um[j] = mono(lg[rowg][l16 + 16 * j]);
                kk[j] = l16 + 16 * j;
            }
#pragma unroll
            for (int t = 0; t < 4; ++t) {
                um[16 + t] = mono(cval[rowg][l16 + 16 * t]);
                kk[16 + t] = ckey[rowg][l16 + 16 * t];
            }
            const float th = select_topk<20>(um, kk, 0u, 31, l16, cval[rowg], ckey[rowg]);
            if (l16 == 0) {
                lg[rowg][254] = th;       // filter threshold for next octet
                LGI(rowg)[255] = 0;       // reset candidate counter
            }
        } else {
            // ---- filtered logit phase: push only survivors (> th) compactly
            float cmrow[4];
#pragma unroll
            for (int r = 0; r < 4; ++r) cmrow[r] = lg[quad * 4 + r][254];
#pragma unroll
            for (int t = 0; t < 4; ++t) {
                const int key = oct * 256 + wave * 64 + t * 16 + l16;
                const size_t kb = (size_t)(b * TK_ + key) * DQ_ + h * DH_ + quad * 8;
                const short8 kh0 = *(const short8*)(Khi + kb);
                const short8 kh1 = *(const short8*)(Khi + kb + 32);
                const short8 kl0 = *(const short8*)(Klo + kb);
                const short8 kl1 = *(const short8*)(Klo + kb + 32);
                floatx4 acc = {};
                acc = __builtin_amdgcn_mfma_f32_16x16x32_bf16(qh[0], kh0, acc, 0, 0, 0);
                acc = __builtin_amdgcn_mfma_f32_16x16x32_bf16(ql[0], kh0, acc, 0, 0, 0);
                acc = __builtin_amdgcn_mfma_f32_16x16x32_bf16(qh[0], kl0, acc, 0, 0, 0);
                acc = __builtin_amdgcn_mfma_f32_16x16x32_bf16(qh[1], kh1, acc, 0, 0, 0);
                acc = __builtin_amdgcn_mfma_f32_16x16x32_bf16(ql[1], kh1, acc, 0, 0, 0);
                acc = __builtin_amdgcn_mfma_f32_16x16x32_bf16(qh[1], kl1, acc, 0, 0, 0);
                const int midx = b * TK_ + key;
                bool masked;
                if (mmode == 2)      masked = ((const u16*)maskp)[midx] != 0;
                else if (mmode == 3) masked = ((const float*)maskp)[midx] != 0.0f;
                else if (mmode == 1) masked = ((const unsigned char*)maskp)[midx] != 0;
                else                 masked = ((const int*)maskp)[midx] != 0;
#pragma unroll
                for (int r = 0; r < 4; ++r) {
                    const float val = masked ? -3.0e38f : definite(acc[r], -3.0e38f);
                    if (val > cmrow[r]) {
                        const int row = quad * 4 + r;
                        const int pos = atomicAdd(&LGI(row)[255], 1);
                        if (pos < 120) {
                            lg[row][pos] = val;
                            LGI(row)[120 + pos] = key;
                        }
                    }
                }
            }
            __syncthreads();

            // ---- compact select: 8 candidates + 4 carry per lane, z-space
            unsigned uc[4]; int ck4[4];
#pragma unroll
            for (int t = 0; t < 4; ++t) {
                uc[t] = mono(cval[rowg][l16 + 16 * t]);
                ck4[t] = ckey[rowg][l16 + 16 * t];
            }
            unsigned cm = uc[0];
            cm = (uc[1] < cm) ? uc[1] : cm;
            cm = (uc[2] < cm) ? uc[2] : cm;
            cm = (uc[3] < cm) ? uc[3] : cm;
            cm = gmin16u(cm);
            int cnt = LGI(rowg)[255];
            if (cnt > 120) cnt = 120;

            unsigned zm[12]; int kk[12];
            unsigned zmx = 0;
#pragma unroll
            for (int i = 0; i < 8; ++i) {
                const int idx = l16 + 16 * i;          // 0..127
                const bool valid = idx < cnt;          // cnt <= 120
                const float v = lg[rowg][idx];
                const int k = LGI(rowg)[120 + idx];
                const unsigned mv = mono(v);
                // CLAMP: th (early-exit X) can sit below the true carry-min cm;
                // mv <= cm candidates can never be in the exact top-64 -> pads.
                const bool live = valid && (mv > cm);
                zm[i] = live ? (mv - cm) : 0u;
                kk[i] = live ? k : 0x7FFFFFFF;
                zmx = (zm[i] > zmx) ? zm[i] : zmx;
            }
#pragma unroll
            for (int t = 0; t < 4; ++t) {
                zm[8 + t] = uc[t] - cm;
                kk[8 + t] = ck4[t];
                zmx = (zm[8 + t] > zmx) ? zm[8 + t] : zmx;
            }
            zmx = gmax16u(zmx);
            const int hb = 31 - __clz(zmx | 1u);
            const float th = select_topk<12>(zm, kk, cm, hb, l16, cval[rowg], ckey[rowg]);
            if (l16 == 0) {
                lg[rowg][254] = th;
                LGI(rowg)[255] = 0;
            }
        }
        if (oct < 7) __syncthreads();   // th/counter + candidate slots reuse
    }
    #undef LGI

    // ---- softmax over 64 kept entries (group-parallel; same-wave LDS ordering)
    {
        float v4[4];
#pragma unroll
        for (int t = 0; t < 4; ++t) v4[t] = cval[rowg][l16 + 16 * t];
        float m = fmaxf(fmaxf(v4[0], v4[1]), fmaxf(v4[2], v4[3]));
        m = gmax16f(m);
        float p4[4], S = 0.f;
#pragma unroll
        for (int t = 0; t < 4; ++t) { p4[t] = __expf(v4[t] - m); S += p4[t]; }
        S = gsum16f(S);
        const float inv = 1.0f / S;
#pragma unroll
        for (int t = 0; t < 4; ++t) cval[rowg][l16 + 16 * t] = p4[t] * inv;
    }

    // ---- weighted bf16-V gather: row-pairs, dword loads (2 dims/lane)
    const int half = lane >> 5, l32 = lane & 31;
    const u16* Vrow = Vb16 + (size_t)b * TK_ * DQ_ + h * DH_ + l32 * 2;
#pragma unroll
    for (int rp = 0; rp < 2; ++rp) {
        const int row = wave * 4 + rp * 2 + half;
        float a0 = 0.f, a1 = 0.f;
#pragma unroll 4
        for (int e = 0; e < 64; ++e) {
            const float w = cval[row][e];
            const int k = ckey[row][e];
            const unsigned v2 = *(const unsigned*)(Vrow + (size_t)k * DQ_);
            a0 += w * bf2f((u16)(v2 & 0xFFFFu));
            a1 += w * bf2f((u16)(v2 >> 16));
        }
        a0 = definite(a0, 0.0f);
        a1 = definite(a1, 0.0f);
        const size_t o = (size_t)(b * TQ_ + q0 + row) * DQ_ + h * DH_ + l32 * 2;
        const u16 h0 = f2bf(a0), h1 = f2bf(a1);
        const u16 l0 = f2bf(a0 - bf2f(h0)), l1 = f2bf(a1 - bf2f(h1));
        *(unsigned*)(attnH + o) = (unsigned)h0 | ((unsigned)h1 << 16);
        *(unsigned*)(attnL + o) = (unsigned)l0 | ((unsigned)l1 << 16);
    }
}

// ---------------------------------------------------------------------------
extern "C" void kernel_launch(void* const* d_in, const int* in_sizes, int n_in,
                              void* d_out, int out_size, void* d_ws, size_t ws_size,
                              hipStream_t stream) {
    static const int exp_sizes[11] = {2097152, 3145728, 4096, 1048576, 1024,
                                      786432, 1024, 786432, 1024, 1048576, 1024};
    if (n_in != 11) {
        marker_kernel<<<(out_size + 255) / 256, 256, 0, stream>>>((float*)d_out, out_size,
                                                                  (float)(150 + n_in));
        return;
    }
    for (int i = 0; i < 11; ++i)
        if (in_sizes[i] != exp_sizes[i]) {
            marker_kernel<<<(out_size + 255) / 256, 256, 0, stream>>>((float*)d_out, out_size,
                                                                      (float)(200 + i));
            return;
        }

    const float* x   = (const float*)d_in[0];
    const float* ctx = (const float*)d_in[1];
    const void*  msk = d_in[2];
    const float* Wq = (const float*)d_in[3];
    const float* bq = (const float*)d_in[4];
    const float* Wk = (const float*)d_in[5];
    const float* bk = (const float*)d_in[6];
    const float* Wv = (const float*)d_in[7];
    const float* bv = (const float*)d_in[8];
    const float* Wo = (const float*)d_in[9];
    const float* bo = (const float*)d_in[10];

    // ---- workspace: exactly 32 MB (verified sufficient)
    const size_t SZ_Q = (size_t)BN_ * TQ_ * DQ_ * 2;   // 4 MB
    const size_t SZ_K = (size_t)BN_ * TK_ * DQ_ * 2;   // 8 MB
    const size_t NEED = 2 * SZ_Q + 2 * SZ_K + SZ_K;    // 32 MB
    if (ws_size < NEED) {
        marker_kernel<<<(out_size + 255) / 256, 256, 0, stream>>>(
            (float*)d_out, out_size, (float)(ws_size >> 20));
        return;
    }

    char* ws = (char*)d_ws;
    u16* Qhi = (u16*)(ws);
    u16* Qlo = (u16*)(ws + SZ_Q);
    u16* Khi = (u16*)(ws + 2 * SZ_Q);
    u16* Klo = (u16*)(ws + 2 * SZ_Q + SZ_K);
    u16* Vb  = (u16*)(ws + 2 * SZ_Q + 2 * SZ_K);

    // weight-split scratch carved from regions dead at that moment:
    u16* WqT_h = Khi;                      // Khi unwritten until K-proj
    u16* WqT_l = Khi + (size_t)DQ_ * DQ_;
    u16* WkT_h = Vb;                       // Vb unwritten until V-proj
    u16* WkT_l = Vb + (size_t)DC_ * DQ_;
    u16* WvT_h = (u16*)d_out;              // d_out dead until final GEMM
    u16* WvT_l = (u16*)d_out + (size_t)DC_ * DQ_;
    u16* WoT_h = Khi;                      // Khi dead after attention
    u16* WoT_l = Khi + (size_t)DQ_ * DQ_;

    const int MQ = BN_ * TQ_;  // 2048
    const int MK = BN_ * TK_;  // 4096

    // Q projection (scale DH^-0.5 folded into the hi/lo split); grid (8,32)
    tsplit<<<dim3(DQ_ / 32, DQ_ / 32), 256, 0, stream>>>(Wq, WqT_h, WqT_l, DQ_, DQ_);
    gemm3<0, 2><<<dim3(DQ_ / 128, MQ / 64), 256, 0, stream>>>(
        x, nullptr, WqT_h, WqT_l, bq, 0.125f, Qhi, Qlo, MQ, DQ_, DQ_);
    // K projection; grid (8,64)
    tsplit<<<dim3(DQ_ / 32, DC_ / 32), 256, 0, stream>>>(Wk, WkT_h, WkT_l, DC_, DQ_);
    gemm3<0, 2><<<dim3(DQ_ / 128, MK / 64), 256, 0, stream>>>(
        ctx, nullptr, WkT_h, WkT_l, bk, 1.0f, Khi, Klo, MK, DQ_, DC_);
    // V projection (bf16 out); grid (8,64)
    tsplit<<<dim3(DQ_ / 32, DC_ / 32), 256, 0, stream>>>(Wv, WvT_h, WvT_l, DC_, DQ_);
    gemm3<0, 1><<<dim3(DQ_ / 128, MK / 64), 256, 0, stream>>>(
        ctx, nullptr, WvT_h, WvT_l, bv, 1.0f, Vb, nullptr, MK, DQ_, DC_);

    // fused top-64 attention; writes attn hi/lo in place over Qhi/Qlo
    attn_topk<<<dim3(TQ_ / 16, NH_, BN_), 256, 0, stream>>>(
        Qhi, Qlo, Khi, Klo, Vb, msk, Qhi, Qlo);

    // output projection: split-A (attn hi/lo), fp32 out; grid (8,32)
    tsplit<<<dim3(DQ_ / 32, DQ_ / 32), 256, 0, stream>>>(Wo, WoT_h, WoT_l, DQ_, DQ_);
    gemm3<1, 0><<<dim3(DQ_ / 128, MQ / 64), 256, 0, stream>>>(
        Qhi, Qlo, WoT_h, WoT_l, bo, 1.0f, d_out, nullptr, MQ, DQ_, DQ_);
}

// Round 14
// 439.131 us; speedup vs baseline: 1.0855x; 1.0855x over previous
//
#include <hip/hip_runtime.h>
#include <cstdint>
#include <cstddef>

// Problem constants (from reference). Inputs/outputs are fp32 (verified round 4).
#define BN_ 2
#define TQ_ 1024
#define TK_ 2048
#define DQ_ 1024
#define DC_ 768
#define NH_ 16
#define DH_ 64
#define TOPK_ 64

typedef unsigned short u16;
typedef __attribute__((ext_vector_type(8))) short short8;   // 8 bf16 MFMA frag
typedef __attribute__((ext_vector_type(8))) u16   ushort8;  // 16B vector load
typedef __attribute__((ext_vector_type(4))) float floatx4;  // MFMA acc / float4

__device__ __forceinline__ float bf2f(u16 u) { return __uint_as_float(((unsigned)u) << 16); }
__device__ __forceinline__ u16 f2bf(float f) {  // round-to-nearest-even
    unsigned u = __float_as_uint(f);
    u += 0x7FFFu + ((u >> 16) & 1u);
    return (u16)(u >> 16);
}
__device__ __forceinline__ float definite(float v, float repl) {
    return ((__float_as_uint(v) & 0x7F800000u) == 0x7F800000u) ? repl : v;
}
// monotone float<->uint mapping (ascending)
__device__ __forceinline__ unsigned mono(float f) {
    unsigned u = __float_as_uint(f);
    return (u & 0x80000000u) ? ~u : (u | 0x80000000u);
}
__device__ __forceinline__ float invmono(unsigned u) {
    return __uint_as_float((u & 0x80000000u) ? (u & 0x7FFFFFFFu) : ~u);
}
// 16-lane-group reductions (xor offsets 1,2,4,8 stay inside row-of-16 -> DPP)
__device__ __forceinline__ int gsum16(int x) {
#pragma unroll
    for (int o = 1; o < 16; o <<= 1) x += __shfl_xor(x, o);
    return x;
}
__device__ __forceinline__ int gmin16(int x) {
#pragma unroll
    for (int o = 1; o < 16; o <<= 1) { int y = __shfl_xor(x, o); x = (y < x) ? y : x; }
    return x;
}
__device__ __forceinline__ unsigned gmin16u(unsigned x) {
#pragma unroll
    for (int o = 1; o < 16; o <<= 1) { unsigned y = __shfl_xor((int)x, o); x = (y < x) ? y : x; }
    return x;
}
__device__ __forceinline__ unsigned gmax16u(unsigned x) {
#pragma unroll
    for (int o = 1; o < 16; o <<= 1) { unsigned y = __shfl_xor((int)x, o); x = (y > x) ? y : x; }
    return x;
}
__device__ __forceinline__ float gmax16f(float x) {
#pragma unroll
    for (int o = 1; o < 16; o <<= 1) x = fmaxf(x, __shfl_xor(x, o));
    return x;
}
__device__ __forceinline__ float gsum16f(float x) {
#pragma unroll
    for (int o = 1; o < 16; o <<= 1) x += __shfl_xor(x, o);
    return x;
}

// diagnostic: fill output with a recognizable constant (fp32 out)
__global__ void marker_kernel(float* __restrict__ out, int n, float val) {
    const int i = blockIdx.x * 256 + threadIdx.x;
    if (i < n) out[i] = val;
}

// ---------------------------------------------------------------------------
// Exact top-64 selection over NV values/lane spread across a 16-lane group.
// um[] mono-mapped (z-biased), kk[] keys; base added back before invmono.
// hb = highest bit to search; early-exit when count==64 (set remains exact:
// {u >= X} has exactly 64). Compact >X then tie-fill ==X ascending-key.
// Returns xval = invmono(base+X). NOTE: with early exit X can be BELOW the
// true min of the kept set — callers using the return as a filter threshold
// must clamp (see compact-select path).
template <int NV>
__device__ __forceinline__ float select_topk(const unsigned (&um)[NV], const int (&kk)[NV],
                                             unsigned base, int hb, int l16,
                                             float* cvrow, int* ckrow) {
    unsigned X = 0u;
    bool done = false;
    for (int bit = hb; bit >= 0; --bit) {
        const unsigned C = X | (1u << bit);
        int c = 0;
#pragma unroll
        for (int j = 0; j < NV; ++j) c += (um[j] >= C) ? 1 : 0;
        c = gsum16(c);
        if (!done && c >= 64) X = C;
        if (c == 64) done = true;
        if (__all(done)) break;
    }
    // compact strictly-greater
    int myGt = 0;
#pragma unroll
    for (int j = 0; j < NV; ++j) myGt += (um[j] > X) ? 1 : 0;
    const int totalGt = gsum16(myGt);
    int pre = myGt;
#pragma unroll
    for (int off = 1; off < 16; off <<= 1) {
        const int tv = __shfl_up(pre, off);
        if (l16 >= off) pre += tv;
    }
    int wpos = pre - myGt;
#pragma unroll
    for (int j = 0; j < NV; ++j) {
        if (um[j] > X) {
            cvrow[wpos] = invmono(base + um[j]);
            ckrow[wpos] = kk[j];
            ++wpos;
        }
    }
    // tie-fill remaining slots with ==X entries, ascending key
    const float xval = invmono(base + X);
    int remaining = 64 - totalGt;
    int pos = totalGt;
    int lastkey = -1;
    while (remaining > 0) {
        int mykey = 0x7FFFFFFF;
#pragma unroll
        for (int j = 0; j < NV; ++j)
            if (um[j] == X && kk[j] > lastkey && kk[j] < mykey) mykey = kk[j];
        const int mn = gmin16(mykey);
        if (mn == 0x7FFFFFFF) break;
        if (mykey == mn) { cvrow[pos] = xval; ckrow[pos] = mn; }
        lastkey = mn;
        ++pos; --remaining;
    }
    return xval;
}

// ---------------------------------------------------------------------------
// Transpose + hi/lo-split: W fp32 [K][N] -> Wh,Wl bf16 [N][K]
__global__ void __launch_bounds__(256) tsplit(const float* __restrict__ W,
                                              u16* __restrict__ Wh, u16* __restrict__ Wl,
                                              int K, int N) {
    __shared__ float t[32][33];
    const int x = threadIdx.x & 31, y = threadIdx.x >> 5;   // y in 0..7
    const int bn = blockIdx.x * 32, bk = blockIdx.y * 32;
#pragma unroll
    for (int i = 0; i < 32; i += 8) t[y + i][x] = W[(size_t)(bk + y + i) * N + bn + x];
    __syncthreads();
#pragma unroll
    for (int i = 0; i < 32; i += 8) {
        const float f = t[x][y + i];            // = W[bk+x][bn+y+i]
        const u16 hi = f2bf(f);
        const size_t o = (size_t)(bn + y + i) * K + bk + x;
        Wh[o] = hi;
        Wl[o] = f2bf(f - bf2f(hi));
    }
}

// ---------------------------------------------------------------------------
// GEMM (round-11 proven): C[M][N] = A[M][K] * W[K][N] + bias, * scale.
// B pre-transposed & split: Bh/Bl bf16 [N][K]. Tile 64(M) x 128(N), BK=64.
// XOR-swizzled UNPADDED LDS: row m chunk c stored at slot m*8 + (c ^ (m&7)).
// 4 waves 2x2: wave tile 32(m) x 64(n) = 2x4 mfma_16x16x32, 3-term split
// (ah*bh + al*bh + ah*bl). LDS 48KB -> 3 WG/CU.
// ASPLIT 0: A fp32 (split at stage). ASPLIT 1: A bf16 hi/lo pair.
// OMODE 0: fp32 out. 1: bf16 out. 2: bf16 hi/lo pair out.
template <int ASPLIT, int OMODE>
__global__ void __launch_bounds__(256) gemm3(
    const void* __restrict__ Ap, const void* __restrict__ Alp,
    const u16* __restrict__ Bh, const u16* __restrict__ Bl,
    const float* __restrict__ bias, float scale,
    void* __restrict__ out0, void* __restrict__ out1,
    int M, int N, int K) {
    __shared__ u16 Ahs[64 * 64];    // 8 KB   [m][k] hi, swizzled
    __shared__ u16 Als[64 * 64];    // 8 KB   lo
    __shared__ u16 Bhs[128 * 64];   // 16 KB  [n][k] hi, swizzled
    __shared__ u16 Bls[128 * 64];   // 16 KB  lo

    const int tid = threadIdx.x;
    const int lane = tid & 63, wave = tid >> 6;
    const int wm = wave >> 1, wn = wave & 1;
    const int quad = lane >> 4, l16 = lane & 15;
    const int bm = blockIdx.y * 64, bn = blockIdx.x * 128;

    floatx4 acc[2][4] = {};

    for (int k0 = 0; k0 < K; k0 += 64) {
        __syncthreads();
        // ---- stage A: 64 rows x 64 cols = 512 slots of 8 elems, 2 per thread
#pragma unroll
        for (int s2 = 0; s2 < 2; ++s2) {
            const int slot = tid + s2 * 256;
            const int m = slot >> 3, cpos = slot & 7;
            const int c = cpos ^ (m & 7);
            const size_t aoff = (size_t)(bm + m) * K + k0 + c * 8;
            if constexpr (ASPLIT == 0) {
                const float* f = (const float*)Ap + aoff;
                const floatx4 a = *(const floatx4*)f;
                const floatx4 b = *(const floatx4*)(f + 4);
                ushort8 hi, lo;
#pragma unroll
                for (int j = 0; j < 4; ++j) {
                    u16 t = f2bf(a[j]);
                    hi[j] = t; lo[j] = f2bf(a[j] - bf2f(t));
                    t = f2bf(b[j]);
                    hi[4 + j] = t; lo[4 + j] = f2bf(b[j] - bf2f(t));
                }
                *(ushort8*)&Ahs[slot * 8] = hi;
                *(ushort8*)&Als[slot * 8] = lo;
            } else {
                *(ushort8*)&Ahs[slot * 8] = *(const ushort8*)((const u16*)Ap  + aoff);
                *(ushort8*)&Als[slot * 8] = *(const ushort8*)((const u16*)Alp + aoff);
            }
        }
        // ---- stage B: 128 rows x 64 cols = 1024 slots, 4 per thread
#pragma unroll
        for (int s4 = 0; s4 < 4; ++s4) {
            const int slot = tid + s4 * 256;
            const int n = slot >> 3, cpos = slot & 7;
            const int c = cpos ^ (n & 7);
            const size_t boff = (size_t)(bn + n) * K + k0 + c * 8;
            *(ushort8*)&Bhs[slot * 8] = *(const ushort8*)(Bh + boff);
            *(ushort8*)&Bls[slot * 8] = *(const ushort8*)(Bl + boff);
        }
        __syncthreads();
#pragma unroll
        for (int s = 0; s < 2; ++s) {
            short8 ah[2], al[2], bh[4], bl[4];
#pragma unroll
            for (int mt = 0; mt < 2; ++mt) {
                const int m = wm * 32 + mt * 16 + l16;
                const int cs = s * 4 + quad;
                const int slot = m * 8 + (cs ^ (m & 7));
                ah[mt] = *(const short8*)&Ahs[slot * 8];
                al[mt] = *(const short8*)&Als[slot * 8];
            }
#pragma unroll
            for (int nt = 0; nt < 4; ++nt) {
                const int n = wn * 64 + nt * 16 + l16;
                const int cs = s * 4 + quad;
                const int slot = n * 8 + (cs ^ (n & 7));
                bh[nt] = *(const short8*)&Bhs[slot * 8];
                bl[nt] = *(const short8*)&Bls[slot * 8];
            }
#pragma unroll
            for (int mt = 0; mt < 2; ++mt)
#pragma unroll
                for (int nt = 0; nt < 4; ++nt) {
                    acc[mt][nt] = __builtin_amdgcn_mfma_f32_16x16x32_bf16(ah[mt], bh[nt], acc[mt][nt], 0, 0, 0);
                    acc[mt][nt] = __builtin_amdgcn_mfma_f32_16x16x32_bf16(al[mt], bh[nt], acc[mt][nt], 0, 0, 0);
                    acc[mt][nt] = __builtin_amdgcn_mfma_f32_16x16x32_bf16(ah[mt], bl[nt], acc[mt][nt], 0, 0, 0);
                }
        }
    }

#pragma unroll
    for (int mt = 0; mt < 2; ++mt) {
#pragma unroll
        for (int nt = 0; nt < 4; ++nt) {
            const int col = bn + wn * 64 + nt * 16 + l16;
            const float bcol = bias[col];
#pragma unroll
            for (int r = 0; r < 4; ++r) {
                const int row = bm + wm * 32 + mt * 16 + quad * 4 + r;
                const float val = definite((acc[mt][nt][r] + bcol) * scale, 0.0f);
                const size_t idx = (size_t)row * N + col;
                if constexpr (OMODE == 0) {
                    ((float*)out0)[idx] = val;
                } else if constexpr (OMODE == 1) {
                    ((u16*)out0)[idx] = f2bf(val);
                } else {
                    const u16 hi = f2bf(val);
                    ((u16*)out0)[idx] = hi;
                    ((u16*)out1)[idx] = f2bf(val - bf2f(hi));
                }
            }
        }
    }
}

// ---------------------------------------------------------------------------
// Fused attention: per WG = one (b, h, 16-query tile).
// Split-bf16 MFMA logits (fp32-accurate). 8 OCTETS of 256 keys — lg 16KB,
// total LDS 24576 B. __launch_bounds__(256,4): VGPR cap 128 so the compiler
// keeps the natural ~64-VGPR working set WITHOUT spilling (round-13's (256,6)
// squeezed VGPRs to 40 and spilled ~180MB of scratch traffic to HBM);
// occupancy is then LDS-limited at 6 WG/CU with 64 VGPRs (512/64 = 8 w/EU).
// Octet 0: full logits in lg[16][256] + 20-value early-exit select.
// Octets 1-7: candidate compaction — logits strictly above the stored filter
// threshold th (float slot 254; X from select, a LOWER BOUND on carry-min)
// pushed via LDS atomic counter (int slot 255) into values [0..119] / keys
// int-slots [120..239] (cap 120; E[n]=32..8, overflow ~impossible & capped
// soundly). Compact select: 12 values/lane (8 cand + 4 carry) in z-space vs
// the TRUE carry-min cm; mono(v) <= cm candidates clamped to inert pads
// (z=0, key=INT_MAX) — the round-11 underflow fix. Selection invariant
// (exact running top-64, ascending-key ties) is partition-independent ->
// same selected set as the quarter scheme. Output hi/lo in-place Qhi/Qlo.
__global__ void __launch_bounds__(256, 4) attn_topk(
    const u16* Qhi, const u16* Qlo,     // aliased with outputs - no __restrict__
    const u16* __restrict__ Khi, const u16* __restrict__ Klo,
    const u16* __restrict__ Vb16, const void* __restrict__ maskp,
    u16* attnH, u16* attnL) {
    __shared__ float lg[16][256];     // 16384 B
    __shared__ float cval[16][64];    // 4096 B
    __shared__ int   ckey[16][64];    // 4096 B  -> total 24576 B
    #define LGI(row) ((int*)&lg[row][0])

    const int tid = threadIdx.x;
    const int lane = tid & 63, wave = tid >> 6;
    const int quad = lane >> 4, l16 = lane & 15;
    const int rowg = wave * 4 + quad;              // this lane's selection row
    const int b = blockIdx.z, h = blockIdx.y, q0 = blockIdx.x * 16;

    // ---- mask dtype probe: per-wave, barrier-free (first 1024 u16 = 2 KB)
    int mmode;
    {
        bool cbyte = false, cbf = false, cf32 = false;
#pragma unroll
        for (int j = 0; j < 16; ++j) {
            const int i = lane + 64 * j;
            const unsigned v = ((const u16*)maskp)[i];
            cbyte |= (v == 0x0100u || v == 0x0101u) || ((i & 1) && v == 0x0001u);
            cbf   |= (!(i & 1)) && v == 0x3F80u;
            cf32  |= (i & 1) && v == 0x3F80u;
        }
        const bool abf = __any(cbf), af32 = __any(cf32), abyte = __any(cbyte);
        mmode = abf ? 2 : (af32 ? 3 : (abyte ? 1 : 0));
    }

    // ---- Q fragments (A-operand: m=lane&15, k=quad*8+j), two k-steps of 32
    short8 qh[2], ql[2];
    {
        const size_t base = (size_t)(b * TQ_ + q0 + l16) * DQ_ + h * DH_ + quad * 8;
        qh[0] = *(const short8*)(Qhi + base);
        qh[1] = *(const short8*)(Qhi + base + 32);
        ql[0] = *(const short8*)(Qlo + base);
        ql[1] = *(const short8*)(Qlo + base + 32);
    }

    // init carry to -inf with distinct keys (first barrier below covers this)
    for (int i = tid; i < 16 * 64; i += 256) {
        cval[i >> 6][i & 63] = __uint_as_float(0xFF800000u);
        ckey[i >> 6][i & 63] = i & 63;
    }

    for (int oct = 0; oct < 8; ++oct) {
        if (oct == 0) {
            // ---- full logit phase: 256 keys, each wave 64 keys x 16 rows
#pragma unroll
            for (int t = 0; t < 4; ++t) {
                const int key = wave * 64 + t * 16 + l16;
                const size_t kb = (size_t)(b * TK_ + key) * DQ_ + h * DH_ + quad * 8;
                const short8 kh0 = *(const short8*)(Khi + kb);
                const short8 kh1 = *(const short8*)(Khi + kb + 32);
                const short8 kl0 = *(const short8*)(Klo + kb);
                const short8 kl1 = *(const short8*)(Klo + kb + 32);
                floatx4 acc = {};
                acc = __builtin_amdgcn_mfma_f32_16x16x32_bf16(qh[0], kh0, acc, 0, 0, 0);
                acc = __builtin_amdgcn_mfma_f32_16x16x32_bf16(ql[0], kh0, acc, 0, 0, 0);
                acc = __builtin_amdgcn_mfma_f32_16x16x32_bf16(qh[0], kl0, acc, 0, 0, 0);
                acc = __builtin_amdgcn_mfma_f32_16x16x32_bf16(qh[1], kh1, acc, 0, 0, 0);
                acc = __builtin_amdgcn_mfma_f32_16x16x32_bf16(ql[1], kh1, acc, 0, 0, 0);
                acc = __builtin_amdgcn_mfma_f32_16x16x32_bf16(qh[1], kl1, acc, 0, 0, 0);
                const int midx = b * TK_ + key;
                bool masked;
                if (mmode == 2)      masked = ((const u16*)maskp)[midx] != 0;
                else if (mmode == 3) masked = ((const float*)maskp)[midx] != 0.0f;
                else if (mmode == 1) masked = ((const unsigned char*)maskp)[midx] != 0;
                else                 masked = ((const int*)maskp)[midx] != 0;
#pragma unroll
                for (int r = 0; r < 4; ++r)
                    lg[quad * 4 + r][key] = masked ? -3.0e38f : definite(acc[r], -3.0e38f);
            }
            __syncthreads();

            // ---- full select over 16 new + 4 carry
            unsigned um[20]; int kk[20];
#pragma unroll
            for (int j = 0; j < 16; ++j) {
                um[j] = mono(lg[rowg][l16 + 16 * j]);
                kk[j] = l16 + 16 * j;
            }
#pragma unroll
            for (int t = 0; t < 4; ++t) {
                um[16 + t] = mono(cval[rowg][l16 + 16 * t]);
                kk[16 + t] = ckey[rowg][l16 + 16 * t];
            }
            const float th = select_topk<20>(um, kk, 0u, 31, l16, cval[rowg], ckey[rowg]);
            if (l16 == 0) {
                lg[rowg][254] = th;       // filter threshold for next octet
                LGI(rowg)[255] = 0;       // reset candidate counter
            }
        } else {
            // ---- filtered logit phase: push only survivors (> th) compactly
            float cmrow[4];
#pragma unroll
            for (int r = 0; r < 4; ++r) cmrow[r] = lg[quad * 4 + r][254];
#pragma unroll
            for (int t = 0; t < 4; ++t) {
                const int key = oct * 256 + wave * 64 + t * 16 + l16;
                const size_t kb = (size_t)(b * TK_ + key) * DQ_ + h * DH_ + quad * 8;
                const short8 kh0 = *(const short8*)(Khi + kb);
                const short8 kh1 = *(const short8*)(Khi + kb + 32);
                const short8 kl0 = *(const short8*)(Klo + kb);
                const short8 kl1 = *(const short8*)(Klo + kb + 32);
                floatx4 acc = {};
                acc = __builtin_amdgcn_mfma_f32_16x16x32_bf16(qh[0], kh0, acc, 0, 0, 0);
                acc = __builtin_amdgcn_mfma_f32_16x16x32_bf16(ql[0], kh0, acc, 0, 0, 0);
                acc = __builtin_amdgcn_mfma_f32_16x16x32_bf16(qh[0], kl0, acc, 0, 0, 0);
                acc = __builtin_amdgcn_mfma_f32_16x16x32_bf16(qh[1], kh1, acc, 0, 0, 0);
                acc = __builtin_amdgcn_mfma_f32_16x16x32_bf16(ql[1], kh1, acc, 0, 0, 0);
                acc = __builtin_amdgcn_mfma_f32_16x16x32_bf16(qh[1], kl1, acc, 0, 0, 0);
                const int midx = b * TK_ + key;
                bool masked;
                if (mmode == 2)      masked = ((const u16*)maskp)[midx] != 0;
                else if (mmode == 3) masked = ((const float*)maskp)[midx] != 0.0f;
                else if (mmode == 1) masked = ((const unsigned char*)maskp)[midx] != 0;
                else                 masked = ((const int*)maskp)[midx] != 0;
#pragma unroll
                for (int r = 0; r < 4; ++r) {
                    const float val = masked ? -3.0e38f : definite(acc[r], -3.0e38f);
                    if (val > cmrow[r]) {
                        const int row = quad * 4 + r;
                        const int pos = atomicAdd(&LGI(row)[255], 1);
                        if (pos < 120) {
                            lg[row][pos] = val;
                            LGI(row)[120 + pos] = key;
                        }
                    }
                }
            }
            __syncthreads();

            // ---- compact select: 8 candidates + 4 carry per lane, z-space
            unsigned uc[4]; int ck4[4];
#pragma unroll
            for (int t = 0; t < 4; ++t) {
                uc[t] = mono(cval[rowg][l16 + 16 * t]);
                ck4[t] = ckey[rowg][l16 + 16 * t];
            }
            unsigned cm = uc[0];
            cm = (uc[1] < cm) ? uc[1] : cm;
            cm = (uc[2] < cm) ? uc[2] : cm;
            cm = (uc[3] < cm) ? uc[3] : cm;
            cm = gmin16u(cm);
            int cnt = LGI(rowg)[255];
            if (cnt > 120) cnt = 120;

            unsigned zm[12]; int kk[12];
            unsigned zmx = 0;
#pragma unroll
            for (int i = 0; i < 8; ++i) {
                const int idx = l16 + 16 * i;          // 0..127
                const bool valid = idx < cnt;          // cnt <= 120
                const float v = lg[rowg][idx];
                const int k = LGI(rowg)[120 + idx];
                const unsigned mv = mono(v);
                // CLAMP: th (early-exit X) can sit below the true carry-min cm;
                // mv <= cm candidates can never be in the exact top-64 -> pads.
                const bool live = valid && (mv > cm);
                zm[i] = live ? (mv - cm) : 0u;
                kk[i] = live ? k : 0x7FFFFFFF;
                zmx = (zm[i] > zmx) ? zm[i] : zmx;
            }
#pragma unroll
            for (int t = 0; t < 4; ++t) {
                zm[8 + t] = uc[t] - cm;
                kk[8 + t] = ck4[t];
                zmx = (zm[8 + t] > zmx) ? zm[8 + t] : zmx;
            }
            zmx = gmax16u(zmx);
            const int hb = 31 - __clz(zmx | 1u);
            const float th = select_topk<12>(zm, kk, cm, hb, l16, cval[rowg], ckey[rowg]);
            if (l16 == 0) {
                lg[rowg][254] = th;
                LGI(rowg)[255] = 0;
            }
        }
        if (oct < 7) __syncthreads();   // th/counter + candidate slots reuse
    }
    #undef LGI

    // ---- softmax over 64 kept entries (group-parallel; same-wave LDS ordering)
    {
        float v4[4];
#pragma unroll
        for (int t = 0; t < 4; ++t) v4[t] = cval[rowg][l16 + 16 * t];
        float m = fmaxf(fmaxf(v4[0], v4[1]), fmaxf(v4[2], v4[3]));
        m = gmax16f(m);
        float p4[4], S = 0.f;
#pragma unroll
        for (int t = 0; t < 4; ++t) { p4[t] = __expf(v4[t] - m); S += p4[t]; }
        S = gsum16f(S);
        const float inv = 1.0f / S;
#pragma unroll
        for (int t = 0; t < 4; ++t) cval[rowg][l16 + 16 * t] = p4[t] * inv;
    }

    // ---- weighted bf16-V gather: row-pairs, dword loads (2 dims/lane)
    const int half = lane >> 5, l32 = lane & 31;
    const u16* Vrow = Vb16 + (size_t)b * TK_ * DQ_ + h * DH_ + l32 * 2;
#pragma unroll
    for (int rp = 0; rp < 2; ++rp) {
        const int row = wave * 4 + rp * 2 + half;
        float a0 = 0.f, a1 = 0.f;
#pragma unroll 4
        for (int e = 0; e < 64; ++e) {
            const float w = cval[row][e];
            const int k = ckey[row][e];
            const unsigned v2 = *(const unsigned*)(Vrow + (size_t)k * DQ_);
            a0 += w * bf2f((u16)(v2 & 0xFFFFu));
            a1 += w * bf2f((u16)(v2 >> 16));
        }
        a0 = definite(a0, 0.0f);
        a1 = definite(a1, 0.0f);
        const size_t o = (size_t)(b * TQ_ + q0 + row) * DQ_ + h * DH_ + l32 * 2;
        const u16 h0 = f2bf(a0), h1 = f2bf(a1);
        const u16 l0 = f2bf(a0 - bf2f(h0)), l1 = f2bf(a1 - bf2f(h1));
        *(unsigned*)(attnH + o) = (unsigned)h0 | ((unsigned)h1 << 16);
        *(unsigned*)(attnL + o) = (unsigned)l0 | ((unsigned)l1 << 16);
    }
}

// ---------------------------------------------------------------------------
extern "C" void kernel_launch(void* const* d_in, const int* in_sizes, int n_in,
                              void* d_out, int out_size, void* d_ws, size_t ws_size,
                              hipStream_t stream) {
    static const int exp_sizes[11] = {2097152, 3145728, 4096, 1048576, 1024,
                                      786432, 1024, 786432, 1024, 1048576, 1024};
    if (n_in != 11) {
        marker_kernel<<<(out_size + 255) / 256, 256, 0, stream>>>((float*)d_out, out_size,
                                                                  (float)(150 + n_in));
        return;
    }
    for (int i = 0; i < 11; ++i)
        if (in_sizes[i] != exp_sizes[i]) {
            marker_kernel<<<(out_size + 255) / 256, 256, 0, stream>>>((float*)d_out, out_size,
                                                                      (float)(200 + i));
            return;
        }

    const float* x   = (const float*)d_in[0];
    const float* ctx = (const float*)d_in[1];
    const void*  msk = d_in[2];
    const float* Wq = (const float*)d_in[3];
    const float* bq = (const float*)d_in[4];
    const float* Wk = (const float*)d_in[5];
    const float* bk = (const float*)d_in[6];
    const float* Wv = (const float*)d_in[7];
    const float* bv = (const float*)d_in[8];
    const float* Wo = (const float*)d_in[9];
    const float* bo = (const float*)d_in[10];

    // ---- workspace: exactly 32 MB (verified sufficient)
    const size_t SZ_Q = (size_t)BN_ * TQ_ * DQ_ * 2;   // 4 MB
    const size_t SZ_K = (size_t)BN_ * TK_ * DQ_ * 2;   // 8 MB
    const size_t NEED = 2 * SZ_Q + 2 * SZ_K + SZ_K;    // 32 MB
    if (ws_size < NEED) {
        marker_kernel<<<(out_size + 255) / 256, 256, 0, stream>>>(
            (float*)d_out, out_size, (float)(ws_size >> 20));
        return;
    }

    char* ws = (char*)d_ws;
    u16* Qhi = (u16*)(ws);
    u16* Qlo = (u16*)(ws + SZ_Q);
    u16* Khi = (u16*)(ws + 2 * SZ_Q);
    u16* Klo = (u16*)(ws + 2 * SZ_Q + SZ_K);
    u16* Vb  = (u16*)(ws + 2 * SZ_Q + 2 * SZ_K);

    // weight-split scratch carved from regions dead at that moment:
    u16* WqT_h = Khi;                      // Khi unwritten until K-proj
    u16* WqT_l = Khi + (size_t)DQ_ * DQ_;
    u16* WkT_h = Vb;                       // Vb unwritten until V-proj
    u16* WkT_l = Vb + (size_t)DC_ * DQ_;
    u16* WvT_h = (u16*)d_out;              // d_out dead until final GEMM
    u16* WvT_l = (u16*)d_out + (size_t)DC_ * DQ_;
    u16* WoT_h = Khi;                      // Khi dead after attention
    u16* WoT_l = Khi + (size_t)DQ_ * DQ_;

    const int MQ = BN_ * TQ_;  // 2048
    const int MK = BN_ * TK_;  // 4096

    // Q projection (scale DH^-0.5 folded into the hi/lo split); grid (8,32)
    tsplit<<<dim3(DQ_ / 32, DQ_ / 32), 256, 0, stream>>>(Wq, WqT_h, WqT_l, DQ_, DQ_);
    gemm3<0, 2><<<dim3(DQ_ / 128, MQ / 64), 256, 0, stream>>>(
        x, nullptr, WqT_h, WqT_l, bq, 0.125f, Qhi, Qlo, MQ, DQ_, DQ_);
    // K projection; grid (8,64)
    tsplit<<<dim3(DQ_ / 32, DC_ / 32), 256, 0, stream>>>(Wk, WkT_h, WkT_l, DC_, DQ_);
    gemm3<0, 2><<<dim3(DQ_ / 128, MK / 64), 256, 0, stream>>>(
        ctx, nullptr, WkT_h, WkT_l, bk, 1.0f, Khi, Klo, MK, DQ_, DC_);
    // V projection (bf16 out); grid (8,64)
    tsplit<<<dim3(DQ_ / 32, DC_ / 32), 256, 0, stream>>>(Wv, WvT_h, WvT_l, DC_, DQ_);
    gemm3<0, 1><<<dim3(DQ_ / 128, MK / 64), 256, 0, stream>>>(
        ctx, nullptr, WvT_h, WvT_l, bv, 1.0f, Vb, nullptr, MK, DQ_, DC_);

    // fused top-64 attention; writes attn hi/lo in place over Qhi/Qlo
    attn_topk<<<dim3(TQ_ / 16, NH_, BN_), 256, 0, stream>>>(
        Qhi, Qlo, Khi, Klo, Vb, msk, Qhi, Qlo);

    // output projection: split-A (attn hi/lo), fp32 out; grid (8,32)
    tsplit<<<dim3(DQ_ / 32, DQ_ / 32), 256, 0, stream>>>(Wo, WoT_h, WoT_l, DQ_, DQ_);
    gemm3<1, 0><<<dim3(DQ_ / 128, MQ / 64), 256, 0, stream>>>(
        Qhi, Qlo, WoT_h, WoT_l, bo, 1.0f, d_out, nullptr, MQ, DQ_, DQ_);
}

// Round 15
// 408.861 us; speedup vs baseline: 1.1658x; 1.0740x over previous
//
#include <hip/hip_runtime.h>
#include <cstdint>
#include <cstddef>

// Problem constants (from reference). Inputs/outputs are fp32 (verified round 4).
#define BN_ 2
#define TQ_ 1024
#define TK_ 2048
#define DQ_ 1024
#define DC_ 768
#define NH_ 16
#define DH_ 64
#define TOPK_ 64

typedef unsigned short u16;
typedef __attribute__((ext_vector_type(8))) short short8;   // 8 bf16 MFMA frag
typedef __attribute__((ext_vector_type(8))) u16   ushort8;  // 16B vector load
typedef __attribute__((ext_vector_type(4))) float floatx4;  // MFMA acc / float4

__device__ __forceinline__ float bf2f(u16 u) { return __uint_as_float(((unsigned)u) << 16); }
__device__ __forceinline__ u16 f2bf(float f) {  // round-to-nearest-even
    unsigned u = __float_as_uint(f);
    u += 0x7FFFu + ((u >> 16) & 1u);
    return (u16)(u >> 16);
}
__device__ __forceinline__ float definite(float v, float repl) {
    return ((__float_as_uint(v) & 0x7F800000u) == 0x7F800000u) ? repl : v;
}
// monotone float<->uint mapping (ascending)
__device__ __forceinline__ unsigned mono(float f) {
    unsigned u = __float_as_uint(f);
    return (u & 0x80000000u) ? ~u : (u | 0x80000000u);
}
__device__ __forceinline__ float invmono(unsigned u) {
    return __uint_as_float((u & 0x80000000u) ? (u & 0x7FFFFFFFu) : ~u);
}
// 16-lane-group reductions (xor offsets 1,2,4,8 stay inside row-of-16 -> DPP)
__device__ __forceinline__ int gsum16(int x) {
#pragma unroll
    for (int o = 1; o < 16; o <<= 1) x += __shfl_xor(x, o);
    return x;
}
__device__ __forceinline__ int gmin16(int x) {
#pragma unroll
    for (int o = 1; o < 16; o <<= 1) { int y = __shfl_xor(x, o); x = (y < x) ? y : x; }
    return x;
}
__device__ __forceinline__ unsigned gmin16u(unsigned x) {
#pragma unroll
    for (int o = 1; o < 16; o <<= 1) { unsigned y = __shfl_xor((int)x, o); x = (y < x) ? y : x; }
    return x;
}
__device__ __forceinline__ unsigned gmax16u(unsigned x) {
#pragma unroll
    for (int o = 1; o < 16; o <<= 1) { unsigned y = __shfl_xor((int)x, o); x = (y > x) ? y : x; }
    return x;
}
__device__ __forceinline__ float gmax16f(float x) {
#pragma unroll
    for (int o = 1; o < 16; o <<= 1) x = fmaxf(x, __shfl_xor(x, o));
    return x;
}
__device__ __forceinline__ float gsum16f(float x) {
#pragma unroll
    for (int o = 1; o < 16; o <<= 1) x += __shfl_xor(x, o);
    return x;
}

// diagnostic: fill output with a recognizable constant (fp32 out)
__global__ void marker_kernel(float* __restrict__ out, int n, float val) {
    const int i = blockIdx.x * 256 + threadIdx.x;
    if (i < n) out[i] = val;
}

// ---------------------------------------------------------------------------
// Exact top-64 selection over NV values/lane spread across a 16-lane group.
// um[] mono-mapped (z-biased), kk[] keys; base added back before invmono.
// hb = highest bit to search; early-exit when count==64 (set remains exact:
// {u >= X} has exactly 64). Compact >X then tie-fill ==X ascending-key.
// Returns xval = invmono(base+X). NOTE: with early exit X can be BELOW the
// true min of the kept set — callers using the return as a filter threshold
// must clamp (see compact-select path).
template <int NV>
__device__ __forceinline__ float select_topk(const unsigned (&um)[NV], const int (&kk)[NV],
                                             unsigned base, int hb, int l16,
                                             float* cvrow, int* ckrow) {
    unsigned X = 0u;
    bool done = false;
    for (int bit = hb; bit >= 0; --bit) {
        const unsigned C = X | (1u << bit);
        int c = 0;
#pragma unroll
        for (int j = 0; j < NV; ++j) c += (um[j] >= C) ? 1 : 0;
        c = gsum16(c);
        if (!done && c >= 64) X = C;
        if (c == 64) done = true;
        if (__all(done)) break;
    }
    // compact strictly-greater
    int myGt = 0;
#pragma unroll
    for (int j = 0; j < NV; ++j) myGt += (um[j] > X) ? 1 : 0;
    const int totalGt = gsum16(myGt);
    int pre = myGt;
#pragma unroll
    for (int off = 1; off < 16; off <<= 1) {
        const int tv = __shfl_up(pre, off);
        if (l16 >= off) pre += tv;
    }
    int wpos = pre - myGt;
#pragma unroll
    for (int j = 0; j < NV; ++j) {
        if (um[j] > X) {
            cvrow[wpos] = invmono(base + um[j]);
            ckrow[wpos] = kk[j];
            ++wpos;
        }
    }
    // tie-fill remaining slots with ==X entries, ascending key
    const float xval = invmono(base + X);
    int remaining = 64 - totalGt;
    int pos = totalGt;
    int lastkey = -1;
    while (remaining > 0) {
        int mykey = 0x7FFFFFFF;
#pragma unroll
        for (int j = 0; j < NV; ++j)
            if (um[j] == X && kk[j] > lastkey && kk[j] < mykey) mykey = kk[j];
        const int mn = gmin16(mykey);
        if (mn == 0x7FFFFFFF) break;
        if (mykey == mn) { cvrow[pos] = xval; ckrow[pos] = mn; }
        lastkey = mn;
        ++pos; --remaining;
    }
    return xval;
}

// ---------------------------------------------------------------------------
// Transpose + hi/lo-split: W fp32 [K][N] -> Wh,Wl bf16 [N][K]
// Batched variant: blockIdx.z selects among up to 3 independent weights
// (saves 2 kernel launches + stream bubbles vs separate dispatches).
struct TsplitJob { const float* W; u16* Wh; u16* Wl; int K; int N; };

__global__ void __launch_bounds__(256) tsplit3(TsplitJob j0, TsplitJob j1, TsplitJob j2) {
    const TsplitJob j = (blockIdx.z == 0) ? j0 : (blockIdx.z == 1) ? j1 : j2;
    const int bk = blockIdx.y * 32;
    if (bk >= j.K) return;                      // grids padded to max K/32
    __shared__ float t[32][33];
    const int x = threadIdx.x & 31, y = threadIdx.x >> 5;   // y in 0..7
    const int bn = blockIdx.x * 32;
#pragma unroll
    for (int i = 0; i < 32; i += 8) t[y + i][x] = j.W[(size_t)(bk + y + i) * j.N + bn + x];
    __syncthreads();
#pragma unroll
    for (int i = 0; i < 32; i += 8) {
        const float f = t[x][y + i];            // = W[bk+x][bn+y+i]
        const u16 hi = f2bf(f);
        const size_t o = (size_t)(bn + y + i) * j.K + bk + x;
        j.Wh[o] = hi;
        j.Wl[o] = f2bf(f - bf2f(hi));
    }
}

__global__ void __launch_bounds__(256) tsplit(const float* __restrict__ W,
                                              u16* __restrict__ Wh, u16* __restrict__ Wl,
                                              int K, int N) {
    __shared__ float t[32][33];
    const int x = threadIdx.x & 31, y = threadIdx.x >> 5;
    const int bn = blockIdx.x * 32, bk = blockIdx.y * 32;
#pragma unroll
    for (int i = 0; i < 32; i += 8) t[y + i][x] = W[(size_t)(bk + y + i) * N + bn + x];
    __syncthreads();
#pragma unroll
    for (int i = 0; i < 32; i += 8) {
        const float f = t[x][y + i];
        const u16 hi = f2bf(f);
        const size_t o = (size_t)(bn + y + i) * K + bk + x;
        Wh[o] = hi;
        Wl[o] = f2bf(f - bf2f(hi));
    }
}

// ---------------------------------------------------------------------------
// GEMM (round-11 proven): C[M][N] = A[M][K] * W[K][N] + bias, * scale.
// B pre-transposed & split: Bh/Bl bf16 [N][K]. Tile 64(M) x 128(N), BK=64.
// XOR-swizzled UNPADDED LDS: row m chunk c stored at slot m*8 + (c ^ (m&7)).
// 4 waves 2x2: wave tile 32(m) x 64(n) = 2x4 mfma_16x16x32, 3-term split
// (ah*bh + al*bh + ah*bl). LDS 48KB -> 3 WG/CU.
// ASPLIT 0: A fp32 (split at stage). ASPLIT 1: A bf16 hi/lo pair.
// OMODE 0: fp32 out. 1: bf16 out. 2: bf16 hi/lo pair out.
template <int ASPLIT, int OMODE>
__global__ void __launch_bounds__(256) gemm3(
    const void* __restrict__ Ap, const void* __restrict__ Alp,
    const u16* __restrict__ Bh, const u16* __restrict__ Bl,
    const float* __restrict__ bias, float scale,
    void* __restrict__ out0, void* __restrict__ out1,
    int M, int N, int K) {
    __shared__ u16 Ahs[64 * 64];    // 8 KB   [m][k] hi, swizzled
    __shared__ u16 Als[64 * 64];    // 8 KB   lo
    __shared__ u16 Bhs[128 * 64];   // 16 KB  [n][k] hi, swizzled
    __shared__ u16 Bls[128 * 64];   // 16 KB  lo

    const int tid = threadIdx.x;
    const int lane = tid & 63, wave = tid >> 6;
    const int wm = wave >> 1, wn = wave & 1;
    const int quad = lane >> 4, l16 = lane & 15;
    const int bm = blockIdx.y * 64, bn = blockIdx.x * 128;

    floatx4 acc[2][4] = {};

    for (int k0 = 0; k0 < K; k0 += 64) {
        __syncthreads();
        // ---- stage A: 64 rows x 64 cols = 512 slots of 8 elems, 2 per thread
#pragma unroll
        for (int s2 = 0; s2 < 2; ++s2) {
            const int slot = tid + s2 * 256;
            const int m = slot >> 3, cpos = slot & 7;
            const int c = cpos ^ (m & 7);
            const size_t aoff = (size_t)(bm + m) * K + k0 + c * 8;
            if constexpr (ASPLIT == 0) {
                const float* f = (const float*)Ap + aoff;
                const floatx4 a = *(const floatx4*)f;
                const floatx4 b = *(const floatx4*)(f + 4);
                ushort8 hi, lo;
#pragma unroll
                for (int j = 0; j < 4; ++j) {
                    u16 t = f2bf(a[j]);
                    hi[j] = t; lo[j] = f2bf(a[j] - bf2f(t));
                    t = f2bf(b[j]);
                    hi[4 + j] = t; lo[4 + j] = f2bf(b[j] - bf2f(t));
                }
                *(ushort8*)&Ahs[slot * 8] = hi;
                *(ushort8*)&Als[slot * 8] = lo;
            } else {
                *(ushort8*)&Ahs[slot * 8] = *(const ushort8*)((const u16*)Ap  + aoff);
                *(ushort8*)&Als[slot * 8] = *(const ushort8*)((const u16*)Alp + aoff);
            }
        }
        // ---- stage B: 128 rows x 64 cols = 1024 slots, 4 per thread
#pragma unroll
        for (int s4 = 0; s4 < 4; ++s4) {
            const int slot = tid + s4 * 256;
            const int n = slot >> 3, cpos = slot & 7;
            const int c = cpos ^ (n & 7);
            const size_t boff = (size_t)(bn + n) * K + k0 + c * 8;
            *(ushort8*)&Bhs[slot * 8] = *(const ushort8*)(Bh + boff);
            *(ushort8*)&Bls[slot * 8] = *(const ushort8*)(Bl + boff);
        }
        __syncthreads();
#pragma unroll
        for (int s = 0; s < 2; ++s) {
            short8 ah[2], al[2], bh[4], bl[4];
#pragma unroll
            for (int mt = 0; mt < 2; ++mt) {
                const int m = wm * 32 + mt * 16 + l16;
                const int cs = s * 4 + quad;
                const int slot = m * 8 + (cs ^ (m & 7));
                ah[mt] = *(const short8*)&Ahs[slot * 8];
                al[mt] = *(const short8*)&Als[slot * 8];
            }
#pragma unroll
            for (int nt = 0; nt < 4; ++nt) {
                const int n = wn * 64 + nt * 16 + l16;
                const int cs = s * 4 + quad;
                const int slot = n * 8 + (cs ^ (n & 7));
                bh[nt] = *(const short8*)&Bhs[slot * 8];
                bl[nt] = *(const short8*)&Bls[slot * 8];
            }
#pragma unroll
            for (int mt = 0; mt < 2; ++mt)
#pragma unroll
                for (int nt = 0; nt < 4; ++nt) {
                    acc[mt][nt] = __builtin_amdgcn_mfma_f32_16x16x32_bf16(ah[mt], bh[nt], acc[mt][nt], 0, 0, 0);
                    acc[mt][nt] = __builtin_amdgcn_mfma_f32_16x16x32_bf16(al[mt], bh[nt], acc[mt][nt], 0, 0, 0);
                    acc[mt][nt] = __builtin_amdgcn_mfma_f32_16x16x32_bf16(ah[mt], bl[nt], acc[mt][nt], 0, 0, 0);
                }
        }
    }

#pragma unroll
    for (int mt = 0; mt < 2; ++mt) {
#pragma unroll
        for (int nt = 0; nt < 4; ++nt) {
            const int col = bn + wn * 64 + nt * 16 + l16;
            const float bcol = bias[col];
#pragma unroll
            for (int r = 0; r < 4; ++r) {
                const int row = bm + wm * 32 + mt * 16 + quad * 4 + r;
                const float val = definite((acc[mt][nt][r] + bcol) * scale, 0.0f);
                const size_t idx = (size_t)row * N + col;
                if constexpr (OMODE == 0) {
                    ((float*)out0)[idx] = val;
                } else if constexpr (OMODE == 1) {
                    ((u16*)out0)[idx] = f2bf(val);
                } else {
                    const u16 hi = f2bf(val);
                    ((u16*)out0)[idx] = hi;
                    ((u16*)out1)[idx] = f2bf(val - bf2f(hi));
                }
            }
        }
    }
}

// ---------------------------------------------------------------------------
// Fused attention (round-11 proven config — best measured: 218 us).
// Per WG = one (b, h, 16-query tile). Split-bf16 MFMA logits (fp32-accurate).
// 4 quarters of 512 keys. Quarter 0: full logits in lg + 36-value early-exit
// select. Quarters 1-3: CANDIDATE COMPACTION — only logits strictly above the
// stored filter threshold th (select's X, a LOWER BOUND on carry-min due to
// early exit) are pushed via LDS atomic into a compact per-row list inside lg
// (values 0..126, keys int-slots 128..254, th at 255, counter at int-slot
// 511). Select runs over 12 values/lane (8 candidates + 4 carry) in z-space
// vs the TRUE carry-min cm; candidates with mono(v) <= cm are CLAMPED to
// inert pads (z=0, key=INT_MAX) — round-10's underflow bug, fixed round 11.
// Octet/6-WG-CU restructures (rounds 12-14) all measured WORSE (occupancy is
// not LDS-limited; ~43% is the grid/barrier ceiling) — do not revisit.
// LDS exactly 40960 B -> 4 WG/CU. Output hi/lo in-place over Qhi/Qlo.
__global__ void __launch_bounds__(256, 4) attn_topk(
    const u16* Qhi, const u16* Qlo,     // aliased with outputs - no __restrict__
    const u16* __restrict__ Khi, const u16* __restrict__ Klo,
    const u16* __restrict__ Vb16, const void* __restrict__ maskp,
    u16* attnH, u16* attnL) {
    __shared__ float lg[16][512];     // 32768 B
    __shared__ float cval[16][64];    // 4096 B
    __shared__ int   ckey[16][64];    // 4096 B  -> total 40960 B

    const int tid = threadIdx.x;
    const int lane = tid & 63, wave = tid >> 6;
    const int quad = lane >> 4, l16 = lane & 15;
    const int rowg = wave * 4 + quad;              // this lane's selection row
    const int b = blockIdx.z, h = blockIdx.y, q0 = blockIdx.x * 16;

    // ---- mask dtype probe: per-wave, barrier-free (first 1024 u16 = 2 KB)
    int mmode;
    {
        bool cbyte = false, cbf = false, cf32 = false;
#pragma unroll
        for (int j = 0; j < 16; ++j) {
            const int i = lane + 64 * j;
            const unsigned v = ((const u16*)maskp)[i];
            cbyte |= (v == 0x0100u || v == 0x0101u) || ((i & 1) && v == 0x0001u);
            cbf   |= (!(i & 1)) && v == 0x3F80u;
            cf32  |= (i & 1) && v == 0x3F80u;
        }
        const bool abf = __any(cbf), af32 = __any(cf32), abyte = __any(cbyte);
        mmode = abf ? 2 : (af32 ? 3 : (abyte ? 1 : 0));
    }

    // ---- Q fragments (A-operand: m=lane&15, k=quad*8+j), two k-steps of 32
    short8 qh[2], ql[2];
    {
        const size_t base = (size_t)(b * TQ_ + q0 + l16) * DQ_ + h * DH_ + quad * 8;
        qh[0] = *(const short8*)(Qhi + base);
        qh[1] = *(const short8*)(Qhi + base + 32);
        ql[0] = *(const short8*)(Qlo + base);
        ql[1] = *(const short8*)(Qlo + base + 32);
    }

    // init carry to -inf with distinct keys (first barrier below covers this)
    for (int i = tid; i < 16 * 64; i += 256) {
        cval[i >> 6][i & 63] = __uint_as_float(0xFF800000u);
        ckey[i >> 6][i & 63] = i & 63;
    }

    for (int qtr = 0; qtr < 4; ++qtr) {
        if (qtr == 0) {
            // ---- full logit phase: write all 512 per row
#pragma unroll 2
            for (int t = 0; t < 8; ++t) {
                const int key = wave * 128 + t * 16 + l16;
                const size_t kb = (size_t)(b * TK_ + key) * DQ_ + h * DH_ + quad * 8;
                const short8 kh0 = *(const short8*)(Khi + kb);
                const short8 kh1 = *(const short8*)(Khi + kb + 32);
                const short8 kl0 = *(const short8*)(Klo + kb);
                const short8 kl1 = *(const short8*)(Klo + kb + 32);
                floatx4 acc = {};
                acc = __builtin_amdgcn_mfma_f32_16x16x32_bf16(qh[0], kh0, acc, 0, 0, 0);
                acc = __builtin_amdgcn_mfma_f32_16x16x32_bf16(ql[0], kh0, acc, 0, 0, 0);
                acc = __builtin_amdgcn_mfma_f32_16x16x32_bf16(qh[0], kl0, acc, 0, 0, 0);
                acc = __builtin_amdgcn_mfma_f32_16x16x32_bf16(qh[1], kh1, acc, 0, 0, 0);
                acc = __builtin_amdgcn_mfma_f32_16x16x32_bf16(ql[1], kh1, acc, 0, 0, 0);
                acc = __builtin_amdgcn_mfma_f32_16x16x32_bf16(qh[1], kl1, acc, 0, 0, 0);
                const int midx = b * TK_ + key;
                bool masked;
                if (mmode == 2)      masked = ((const u16*)maskp)[midx] != 0;
                else if (mmode == 3) masked = ((const float*)maskp)[midx] != 0.0f;
                else if (mmode == 1) masked = ((const unsigned char*)maskp)[midx] != 0;
                else                 masked = ((const int*)maskp)[midx] != 0;
#pragma unroll
                for (int r = 0; r < 4; ++r)
                    lg[quad * 4 + r][key] = masked ? -3.0e38f : definite(acc[r], -3.0e38f);
            }
            __syncthreads();

            // ---- full select over 32 new + 4 carry
            unsigned um[36]; int kk[36];
#pragma unroll
            for (int j = 0; j < 32; ++j) {
                um[j] = mono(lg[rowg][l16 + 16 * j]);
                kk[j] = l16 + 16 * j;
            }
#pragma unroll
            for (int t = 0; t < 4; ++t) {
                um[32 + t] = mono(cval[rowg][l16 + 16 * t]);
                kk[32 + t] = ckey[rowg][l16 + 16 * t];
            }
            const float th = select_topk<36>(um, kk, 0u, 31, l16, cval[rowg], ckey[rowg]);
            if (l16 == 0) {
                lg[rowg][255] = th;                 // filter threshold for next qtr
                ((int*)&lg[rowg][0])[511] = 0;      // reset candidate counter
            }
        } else {
            // ---- filtered logit phase: push only survivors (> th) compactly
            float cmrow[4];
#pragma unroll
            for (int r = 0; r < 4; ++r) cmrow[r] = lg[quad * 4 + r][255];
#pragma unroll 2
            for (int t = 0; t < 8; ++t) {
                const int key = qtr * 512 + wave * 128 + t * 16 + l16;
                const size_t kb = (size_t)(b * TK_ + key) * DQ_ + h * DH_ + quad * 8;
                const short8 kh0 = *(const short8*)(Khi + kb);
                const short8 kh1 = *(const short8*)(Khi + kb + 32);
                const short8 kl0 = *(const short8*)(Klo + kb);
                const short8 kl1 = *(const short8*)(Klo + kb + 32);
                floatx4 acc = {};
                acc = __builtin_amdgcn_mfma_f32_16x16x32_bf16(qh[0], kh0, acc, 0, 0, 0);
                acc = __builtin_amdgcn_mfma_f32_16x16x32_bf16(ql[0], kh0, acc, 0, 0, 0);
                acc = __builtin_amdgcn_mfma_f32_16x16x32_bf16(qh[0], kl0, acc, 0, 0, 0);
                acc = __builtin_amdgcn_mfma_f32_16x16x32_bf16(qh[1], kh1, acc, 0, 0, 0);
                acc = __builtin_amdgcn_mfma_f32_16x16x32_bf16(ql[1], kh1, acc, 0, 0, 0);
                acc = __builtin_amdgcn_mfma_f32_16x16x32_bf16(qh[1], kl1, acc, 0, 0, 0);
                const int midx = b * TK_ + key;
                bool masked;
                if (mmode == 2)      masked = ((const u16*)maskp)[midx] != 0;
                else if (mmode == 3) masked = ((const float*)maskp)[midx] != 0.0f;
                else if (mmode == 1) masked = ((const unsigned char*)maskp)[midx] != 0;
                else                 masked = ((const int*)maskp)[midx] != 0;
#pragma unroll
                for (int r = 0; r < 4; ++r) {
                    const float val = masked ? -3.0e38f : definite(acc[r], -3.0e38f);
                    if (val > cmrow[r]) {
                        const int row = quad * 4 + r;
                        const int pos = atomicAdd((int*)&lg[row][511], 1);
                        if (pos < 127) {
                            lg[row][pos] = val;
                            ((int*)&lg[row][0])[128 + pos] = key;
                        }
                    }
                }
            }
            __syncthreads();

            // ---- compact select: 8 candidates + 4 carry per lane, z-space
            unsigned uc[4]; int ck4[4];
#pragma unroll
            for (int t = 0; t < 4; ++t) {
                uc[t] = mono(cval[rowg][l16 + 16 * t]);
                ck4[t] = ckey[rowg][l16 + 16 * t];
            }
            unsigned cm = uc[0];
            cm = (uc[1] < cm) ? uc[1] : cm;
            cm = (uc[2] < cm) ? uc[2] : cm;
            cm = (uc[3] < cm) ? uc[3] : cm;
            cm = gmin16u(cm);
            int cnt = ((int*)&lg[rowg][0])[511];
            if (cnt > 127) cnt = 127;

            unsigned zm[12]; int kk[12];
            unsigned zmx = 0;
#pragma unroll
            for (int i = 0; i < 8; ++i) {
                const int idx = l16 + 16 * i;          // 0..127
                const bool valid = idx < cnt;
                const float v = lg[rowg][idx];
                const int k = ((int*)&lg[rowg][0])[128 + idx];
                const unsigned mv = mono(v);
                // CLAMP: th (early-exit X) can sit below the true carry-min cm;
                // mv <= cm candidates can never be in the exact top-64 -> pads.
                const bool live = valid && (mv > cm);
                zm[i] = live ? (mv - cm) : 0u;
                kk[i] = live ? k : 0x7FFFFFFF;
                zmx = (zm[i] > zmx) ? zm[i] : zmx;
            }
#pragma unroll
            for (int t = 0; t < 4; ++t) {
                zm[8 + t] = uc[t] - cm;
                kk[8 + t] = ck4[t];
                zmx = (zm[8 + t] > zmx) ? zm[8 + t] : zmx;
            }
            zmx = gmax16u(zmx);
            const int hb = 31 - __clz(zmx | 1u);
            const float th = select_topk<12>(zm, kk, cm, hb, l16, cval[rowg], ckey[rowg]);
            if (l16 == 0) {
                lg[rowg][255] = th;
                ((int*)&lg[rowg][0])[511] = 0;
            }
        }
        if (qtr < 3) __syncthreads();   // th/counter + lg reuse next quarter
    }

    // ---- softmax over 64 kept entries (group-parallel; same-wave LDS ordering)
    {
        float v4[4];
#pragma unroll
        for (int t = 0; t < 4; ++t) v4[t] = cval[rowg][l16 + 16 * t];
        float m = fmaxf(fmaxf(v4[0], v4[1]), fmaxf(v4[2], v4[3]));
        m = gmax16f(m);
        float p4[4], S = 0.f;
#pragma unroll
        for (int t = 0; t < 4; ++t) { p4[t] = __expf(v4[t] - m); S += p4[t]; }
        S = gsum16f(S);
        const float inv = 1.0f / S;
#pragma unroll
        for (int t = 0; t < 4; ++t) cval[rowg][l16 + 16 * t] = p4[t] * inv;
    }

    // ---- weighted bf16-V gather: row-pairs, dword loads (2 dims/lane)
    const int half = lane >> 5, l32 = lane & 31;
    const u16* Vrow = Vb16 + (size_t)b * TK_ * DQ_ + h * DH_ + l32 * 2;
#pragma unroll
    for (int rp = 0; rp < 2; ++rp) {
        const int row = wave * 4 + rp * 2 + half;
        float a0 = 0.f, a1 = 0.f;
#pragma unroll 4
        for (int e = 0; e < 64; ++e) {
            const float w = cval[row][e];
            const int k = ckey[row][e];
            const unsigned v2 = *(const unsigned*)(Vrow + (size_t)k * DQ_);
            a0 += w * bf2f((u16)(v2 & 0xFFFFu));
            a1 += w * bf2f((u16)(v2 >> 16));
        }
        a0 = definite(a0, 0.0f);
        a1 = definite(a1, 0.0f);
        const size_t o = (size_t)(b * TQ_ + q0 + row) * DQ_ + h * DH_ + l32 * 2;
        const u16 h0 = f2bf(a0), h1 = f2bf(a1);
        const u16 l0 = f2bf(a0 - bf2f(h0)), l1 = f2bf(a1 - bf2f(h1));
        *(unsigned*)(attnH + o) = (unsigned)h0 | ((unsigned)h1 << 16);
        *(unsigned*)(attnL + o) = (unsigned)l0 | ((unsigned)l1 << 16);
    }
}

// ---------------------------------------------------------------------------
extern "C" void kernel_launch(void* const* d_in, const int* in_sizes, int n_in,
                              void* d_out, int out_size, void* d_ws, size_t ws_size,
                              hipStream_t stream) {
    static const int exp_sizes[11] = {2097152, 3145728, 4096, 1048576, 1024,
                                      786432, 1024, 786432, 1024, 1048576, 1024};
    if (n_in != 11) {
        marker_kernel<<<(out_size + 255) / 256, 256, 0, stream>>>((float*)d_out, out_size,
                                                                  (float)(150 + n_in));
        return;
    }
    for (int i = 0; i < 11; ++i)
        if (in_sizes[i] != exp_sizes[i]) {
            marker_kernel<<<(out_size + 255) / 256, 256, 0, stream>>>((float*)d_out, out_size,
                                                                      (float)(200 + i));
            return;
        }

    const float* x   = (const float*)d_in[0];
    const float* ctx = (const float*)d_in[1];
    const void*  msk = d_in[2];
    const float* Wq = (const float*)d_in[3];
    const float* bq = (const float*)d_in[4];
    const float* Wk = (const float*)d_in[5];
    const float* bk = (const float*)d_in[6];
    const float* Wv = (const float*)d_in[7];
    const float* bv = (const float*)d_in[8];
    const float* Wo = (const float*)d_in[9];
    const float* bo = (const float*)d_in[10];

    // ---- workspace: exactly 32 MB (verified sufficient)
    const size_t SZ_Q = (size_t)BN_ * TQ_ * DQ_ * 2;   // 4 MB
    const size_t SZ_K = (size_t)BN_ * TK_ * DQ_ * 2;   // 8 MB
    const size_t NEED = 2 * SZ_Q + 2 * SZ_K + SZ_K;    // 32 MB
    if (ws_size < NEED) {
        marker_kernel<<<(out_size + 255) / 256, 256, 0, stream>>>(
            (float*)d_out, out_size, (float)(ws_size >> 20));
        return;
    }

    char* ws = (char*)d_ws;
    u16* Qhi = (u16*)(ws);
    u16* Qlo = (u16*)(ws + SZ_Q);
    u16* Khi = (u16*)(ws + 2 * SZ_Q);
    u16* Klo = (u16*)(ws + 2 * SZ_Q + SZ_K);
    u16* Vb  = (u16*)(ws + 2 * SZ_Q + 2 * SZ_K);

    // weight-split scratch carved from regions dead at that moment:
    u16* WqT_h = Khi;                      // Khi unwritten until K-proj
    u16* WqT_l = Khi + (size_t)DQ_ * DQ_;
    u16* WkT_h = Vb;                       // Vb unwritten until V-proj
    u16* WkT_l = Vb + (size_t)DC_ * DQ_;
    u16* WvT_h = (u16*)d_out;              // d_out dead until final GEMM
    u16* WvT_l = (u16*)d_out + (size_t)DC_ * DQ_;
    u16* WoT_h = Khi;                      // Khi dead after attention
    u16* WoT_l = Khi + (size_t)DQ_ * DQ_;

    const int MQ = BN_ * TQ_;  // 2048
    const int MK = BN_ * TK_;  // 4096

    // Batched pre-attention weight transposes (Wq/Wk/Wv) in one launch;
    // grid y padded to max K/32 = 32, z selects the job.
    TsplitJob jq{Wq, WqT_h, WqT_l, DQ_, DQ_};
    TsplitJob jk{Wk, WkT_h, WkT_l, DC_, DQ_};
    TsplitJob jv{Wv, WvT_h, WvT_l, DC_, DQ_};
    tsplit3<<<dim3(DQ_ / 32, DQ_ / 32, 3), 256, 0, stream>>>(jq, jk, jv);

    // Q projection (scale DH^-0.5 folded into the hi/lo split); grid (8,32)
    gemm3<0, 2><<<dim3(DQ_ / 128, MQ / 64), 256, 0, stream>>>(
        x, nullptr, WqT_h, WqT_l, bq, 0.125f, Qhi, Qlo, MQ, DQ_, DQ_);
    // K projection; grid (8,64)
    gemm3<0, 2><<<dim3(DQ_ / 128, MK / 64), 256, 0, stream>>>(
        ctx, nullptr, WkT_h, WkT_l, bk, 1.0f, Khi, Klo, MK, DQ_, DC_);
    // V projection (bf16 out); grid (8,64)
    gemm3<0, 1><<<dim3(DQ_ / 128, MK / 64), 256, 0, stream>>>(
        ctx, nullptr, WvT_h, WvT_l, bv, 1.0f, Vb, nullptr, MK, DQ_, DC_);

    // fused top-64 attention; writes attn hi/lo in place over Qhi/Qlo
    attn_topk<<<dim3(TQ_ / 16, NH_, BN_), 256, 0, stream>>>(
        Qhi, Qlo, Khi, Klo, Vb, msk, Qhi, Qlo);

    // output projection: split-A (attn hi/lo), fp32 out; grid (8,32)
    tsplit<<<dim3(DQ_ / 32, DQ_ / 32), 256, 0, stream>>>(Wo, WoT_h, WoT_l, DQ_, DQ_);
    gemm3<1, 0><<<dim3(DQ_ / 128, MQ / 64), 256, 0, stream>>>(
        Qhi, Qlo, WoT_h, WoT_l, bo, 1.0f, d_out, nullptr, MQ, DQ_, DQ_);
}